// Round 8
// baseline (430.420 us; speedup 1.0000x reference)
//
#include <hip/hip_runtime.h>
#include <cstddef>

#define BH   16
#define LSEQ 4096
#define DK   128
#define DV   128
#define C    32
#define NCH  128
#define DVB  16      // dv per scan block
#define NDVB 8
#define PP   136     // prep row-plane pitch (shorts)
#define PC   40      // pitch for [*][32] col planes (kT/vT/T/uT)
#define PS   136     // ST pitch
#define AP   33      // fp32 pitch for 32x32 A

// per-(bh,chunk) contiguous record in workspace (shorts):
// [QH 4096 | WH 4096 | WL 4096 | KTH 4096 | KTL 4096 | ATH 1024 | ATL 1024]
#define RECSZ 22528
#define OQ    0
#define OWH   4096
#define OWL   8192
#define OKTH  12288
#define OKTL  16384
#define OATH  20480
#define OATL  21504

typedef __attribute__((ext_vector_type(4))) float f32x4;
typedef __attribute__((ext_vector_type(8))) short short8;
typedef __attribute__((ext_vector_type(4))) short s16x4;

// split-bf16: x ~= hi + lo, each bf16 rne. Returns (hi<<16)|lo.
__device__ inline unsigned split_bf16(float x) {
    unsigned u = __builtin_bit_cast(unsigned, x);
    unsigned r = u + 0x7fffu + ((u >> 16) & 1u);
    unsigned h = r >> 16;
    float hf = __builtin_bit_cast(float, r & 0xffff0000u);
    float res = x - hf;
    unsigned u2 = __builtin_bit_cast(unsigned, res);
    unsigned r2 = u2 + 0x7fffu + ((u2 >> 16) & 1u);
    return (h << 16) | (r2 >> 16);
}
__device__ inline short hi_bf16(float x) {
    unsigned u = __builtin_bit_cast(unsigned, x);
    return (short)((u + 0x7fffu + ((u >> 16) & 1u)) >> 16);
}
__device__ inline short trunc_bf16(float x) {   // x already exactly bf16
    return (short)(__builtin_bit_cast(unsigned, x) >> 16);
}

// classic pitched frag load: lane holds P[row0+(lane&15)][k0 + (lane>>4)*8 + j]
__device__ inline short8 fld(const short* P, int row0, int pitch, int k0, int lane) {
    return *(const short8*)(P + (row0 + (lane & 15)) * pitch + k0 + ((lane >> 4) << 3));
}
// swizzled pitch-128 plane frag load ([32][128], chunk c XOR row&7)
__device__ inline short8 fldz128(const short* P, int row0, int ks, int lane) {
    int row = row0 + (lane & 15);
    int c = ks * 4 + (lane >> 4);
    return *(const short8*)(P + row * 128 + ((c ^ (row & 7)) << 3));
}
// swizzled pitch-32 plane frag load ([*][32], chunk c XOR row&3), K=32
__device__ inline short8 fldz32(const short* P, int row0, int lane) {
    int row = row0 + (lane & 15);
    int c = lane >> 4;
    return *(const short8*)(P + row * 32 + ((c ^ (row & 3)) << 3));
}
__device__ inline f32x4 mf(short8 a, short8 b, f32x4 c) {
    return __builtin_amdgcn_mfma_f32_16x16x32_bf16(a, b, c, 0, 0, 0);
}
__device__ inline void build_ifrags(int lane, short8& Iev, short8& Iod) {
    int n = lane & 15, q = lane >> 4;
#pragma unroll
    for (int j = 0; j < 8; ++j) {
        Iev[j] = (q * 8 + j == n)      ? (short)0x3F80 : (short)0;
        Iod[j] = (q * 8 + j == n + 16) ? (short)0x3F80 : (short)0;
    }
}
// global swizzled stores (8B), matching the fldz layouts
__device__ inline void store8_z128(short* Pg, int row, int col0, s16x4 v) {
    int c = col0 >> 3;
    *(s16x4*)(Pg + row * 128 + ((c ^ (row & 7)) << 3) + (col0 & 7)) = v;
}
__device__ inline void store8_z32(short* Pg, int row, int col0, s16x4 v) {
    int c = col0 >> 3;
    *(s16x4*)(Pg + row * 32 + ((c ^ (row & 3)) << 3) + (col0 & 7)) = v;
}
// async global->LDS, 1KB per wave-call (lane i -> ldsbase + i*16)
__device__ inline void dma1k(const short* g, short* l, int lane) {
    __builtin_amdgcn_global_load_lds(
        (const __attribute__((address_space(1))) unsigned int*)(g + lane * 8),
        (__attribute__((address_space(3))) unsigned int*)l, 16, 0, 0);
}

// ---------------------------------------------------------------------------
// Kernel 1: per-chunk precompute (unchanged from round 7). 512 threads.
// ---------------------------------------------------------------------------
__global__ __launch_bounds__(512) void k_prep(const float* __restrict__ Q,
                                              const float* __restrict__ K,
                                              const float* __restrict__ V,
                                              const float* __restrict__ Beta,
                                              short* __restrict__ RECg,
                                              float* __restrict__ Uws) {
    __shared__ short knh[C * PP], knl[C * PP], vh[C * PP], vl[C * PP], qh[C * PP];
    __shared__ short knTh[DK * PC], knTl[DK * PC], vTh[DK * PC], vTl[DK * PC];
    __shared__ short Th[C * PC], Tl[C * PC];
    __shared__ float A[C * AP];
    __shared__ float sbeta[C];

    const int t = threadIdx.x, lane = t & 63, wv = t >> 6;
    const int quad = (t >> 4) & 3, l15 = t & 15;
    const int g = blockIdx.x;                       // bh*128 + cid
    const size_t base = (size_t)g * (C * DK);
    short* rec = RECg + (size_t)g * RECSZ;
    short8 Iev, Iod;
    build_ifrags(lane, Iev, Iod);

    if (t < C) sbeta[t] = Beta[(size_t)(g >> 7) * LSEQ + (size_t)(g & 127) * C + t];

    // ---- P0: load K,V,Q (8 floats/thread); norms; row planes + QH record ----
    {
        const int sr = t >> 4, sc = (t & 15) * 8;
        f32x4 kk[2], vv[2], qq[2];
#pragma unroll
        for (int g4 = 0; g4 < 2; ++g4) {
            kk[g4] = *(const f32x4*)(K + base + 8 * t + 4 * g4);
            vv[g4] = *(const f32x4*)(V + base + 8 * t + 4 * g4);
            qq[g4] = *(const f32x4*)(Q + base + 8 * t + 4 * g4);
        }
        float ssk = 0.f, ssq = 0.f;
#pragma unroll
        for (int g4 = 0; g4 < 2; ++g4) {
#pragma unroll
            for (int e = 0; e < 4; ++e) {
                ssk += kk[g4][e] * kk[g4][e];
                ssq += qq[g4][e] * qq[g4][e];
            }
        }
        ssk += __shfl_xor(ssk, 1); ssk += __shfl_xor(ssk, 2);
        ssk += __shfl_xor(ssk, 4); ssk += __shfl_xor(ssk, 8);
        ssq += __shfl_xor(ssq, 1); ssq += __shfl_xor(ssq, 2);
        ssq += __shfl_xor(ssq, 4); ssq += __shfl_xor(ssq, 8);
        const float rk = rsqrtf(ssk + 1e-6f), rq = rsqrtf(ssq + 1e-6f);
        short8 h8, l8, q8;
#pragma unroll
        for (int e = 0; e < 8; ++e) {
            unsigned p = split_bf16(kk[e >> 2][e & 3] * rk);
            h8[e] = (short)(p >> 16); l8[e] = (short)(p & 0xffffu);
        }
        *(short8*)(knh + sr * PP + sc) = h8;
        *(short8*)(knl + sr * PP + sc) = l8;
#pragma unroll
        for (int e = 0; e < 8; ++e) {
            unsigned p = split_bf16(vv[e >> 2][e & 3]);
            h8[e] = (short)(p >> 16); l8[e] = (short)(p & 0xffffu);
        }
        *(short8*)(vh + sr * PP + sc) = h8;
        *(short8*)(vl + sr * PP + sc) = l8;
#pragma unroll
        for (int e = 0; e < 8; ++e) q8[e] = hi_bf16(qq[e >> 2][e & 3] * rq);
        *(short8*)(qh + sr * PP + sc) = q8;
        int c = sc >> 3;
        *(short8*)(rec + OQ + sr * 128 + ((c ^ (sr & 7)) << 3)) = q8;
    }
    __syncthreads();

    // ---- P1: G tiles -> A (strict lower, -beta scaled); attn tiles -> record ----
    if (wv < 3) {
        const int a0 = (wv == 0) ? 0 : 16;      // m rows (ci for attn)
        const int b0 = (wv == 2) ? 16 : 0;      // n rows (cj for attn)
        f32x4 acc = {0.f, 0.f, 0.f, 0.f};
#pragma unroll
        for (int ks = 0; ks < 4; ++ks) {
            short8 ah = fld(knh, a0, PP, ks * 32, lane);
            short8 al = fld(knl, a0, PP, ks * 32, lane);
            short8 bh_ = fld(knh, b0, PP, ks * 32, lane);
            short8 bl_ = fld(knl, b0, PP, ks * 32, lane);
            acc = mf(ah, bh_, mf(ah, bl_, mf(al, bh_, acc)));
        }
#pragma unroll
        for (int r = 0; r < 4; ++r) {
            int row = a0 + quad * 4 + r, col = b0 + l15;
            A[row * AP + col] = (row > col) ? -sbeta[row] * acc[r] : 0.f;
        }
        // attn tile: A-op = kn rows cj (m=cj), B-op = qh rows ci (n=ci)
        f32x4 at = {0.f, 0.f, 0.f, 0.f};
#pragma unroll
        for (int ks = 0; ks < 4; ++ks) {
            short8 kh_ = fld(knh, b0, PP, ks * 32, lane);
            short8 kl_ = fld(knl, b0, PP, ks * 32, lane);
            short8 qf = fld(qh, a0, PP, ks * 32, lane);
            at = mf(kh_, qf, mf(kl_, qf, at));
        }
        s16x4 h4, l4;
#pragma unroll
        for (int r = 0; r < 4; ++r) {
            int cj = b0 + quad * 4 + r, ci = a0 + l15;
            float v = (cj <= ci) ? at[r] : 0.f;
            unsigned p = split_bf16(v);
            h4[r] = (short)(p >> 16); l4[r] = (short)(p & 0xffffu);
        }
        store8_z32(rec + OATH, a0 + l15, b0 + quad * 4, h4);
        store8_z32(rec + OATL, a0 + l15, b0 + quad * 4, l4);
    } else if (wv == 3) {
        // zero the (rows 0-15, cols 16-31) upper tile of A and attn
#pragma unroll
        for (int r = 0; r < 4; ++r) A[l15 * AP + 16 + quad * 4 + r] = 0.f;
        s16x4 z = {0, 0, 0, 0};
        store8_z32(rec + OATH, l15, 16 + quad * 4, z);
        store8_z32(rec + OATL, l15, 16 + quad * 4, z);
    }
    __syncthreads();

    // ---- P2: transposes split by c0-half across wave pairs; subst on wv3 ----
    auto tplane1 = [&](const short* src, short* dst, short* gdst, int c0) {
#pragma unroll
        for (int ks = 0; ks < 4; ++ks) {
            short8 fr = fld(src, c0, PP, ks * 32, lane);
            f32x4 z = {0.f, 0.f, 0.f, 0.f};
            f32x4 cA = mf(fr, Iev, z);
            f32x4 cB = mf(fr, Iod, z);
            s16x4 sA, sB;
#pragma unroll
            for (int r = 0; r < 4; ++r) { sA[r] = trunc_bf16(cA[r]); sB[r] = trunc_bf16(cB[r]); }
            *(s16x4*)(dst + (ks * 32 + l15) * PC + c0 + quad * 4) = sA;
            *(s16x4*)(dst + (ks * 32 + 16 + l15) * PC + c0 + quad * 4) = sB;
            if (gdst) {
                store8_z32(gdst, ks * 32 + l15, c0 + quad * 4, sA);
                store8_z32(gdst, ks * 32 + 16 + l15, c0 + quad * 4, sB);
            }
        }
    };
    if (wv == 0)      tplane1(knh, knTh, rec + OKTH, 0);
    else if (wv == 4) tplane1(knh, knTh, rec + OKTH, 16);
    else if (wv == 1) tplane1(knl, knTl, rec + OKTL, 0);
    else if (wv == 5) tplane1(knl, knTl, rec + OKTL, 16);
    else if (wv == 2) tplane1(vh, vTh, nullptr, 0);
    else if (wv == 6) tplane1(vh, vTh, nullptr, 16);
    else if (wv == 7) { tplane1(vl, vTl, nullptr, 0); tplane1(vl, vTl, nullptr, 16); }
    else if (lane < C) {
        const int j = lane;       // forward substitution (upper of A is zero)
        for (int i = 1; i < C; ++i) {
            float upd = 0.f;
            for (int kk2 = 1; kk2 < i; ++kk2) upd += A[i * AP + kk2] * A[kk2 * AP + j];
            if (j < i) A[i * AP + j] += upd;
        }
    }
    __syncthreads();

    // ---- P3: T' = (A + I) * diag(beta) -> Th/Tl ----
    if (t < 256) {
        int tr = t >> 3, tc = (t & 7) * 4;
        s16x4 h4, l4;
#pragma unroll
        for (int e = 0; e < 4; ++e) {
            int j = tc + e;
            float val = ((tr == j) ? 1.f : (tr > j ? A[tr * AP + j] : 0.f)) * sbeta[j];
            unsigned p = split_bf16(val);
            h4[e] = (short)(p >> 16); l4[e] = (short)(p & 0xffffu);
        }
        *(s16x4*)(Th + tr * PC + tc) = h4;
        *(s16x4*)(Tl + tr * PC + tc) = l4;
    }
    __syncthreads();

    // ---- P4: u = T'@v (fp32 -> Uws) on wv0-3, w = T'@kn (split) on wv4-7 ----
    {
        const int ci0 = (wv & 1) * 16;
        short8 bTh = fld(Th, ci0, PC, 0, lane);
        short8 bTl = fld(Tl, ci0, PC, 0, lane);
        if (wv < 4) {
            const int tb = (wv >> 1) * 4;       // slab range: 0-3 or 4-7
#pragma unroll
            for (int k = 0; k < 4; ++k) {
                int tt = tb + k;
                short8 ah = fld(vTh, tt * 16, PC, 0, lane);
                short8 al = fld(vTl, tt * 16, PC, 0, lane);
                f32x4 z = {0.f, 0.f, 0.f, 0.f};
                f32x4 acc = mf(ah, bTh, mf(ah, bTl, mf(al, bTh, z)));
                *(f32x4*)(Uws + (size_t)g * 4096 + (size_t)(ci0 + l15) * DK + tt * 16 + quad * 4) = acc;
            }
        } else {
            const int tb = ((wv - 4) >> 1) * 4;
#pragma unroll
            for (int k = 0; k < 4; ++k) {
                int tt = tb + k;
                short8 ah = fld(knTh, tt * 16, PC, 0, lane);
                short8 al = fld(knTl, tt * 16, PC, 0, lane);
                f32x4 z = {0.f, 0.f, 0.f, 0.f};
                f32x4 acc = mf(ah, bTh, mf(ah, bTl, mf(al, bTh, z)));
                s16x4 h4, l4;
#pragma unroll
                for (int r = 0; r < 4; ++r) {
                    unsigned p = split_bf16(acc[r]);
                    h4[r] = (short)(p >> 16); l4[r] = (short)(p & 0xffffu);
                }
                store8_z128(rec + OWH, ci0 + l15, tt * 16 + quad * 4, h4);
                store8_z128(rec + OWL, ci0 + l15, tt * 16 + quad * 4, l4);
            }
        }
    }
}

// ---------------------------------------------------------------------------
// Kernel 2: sequential chunk scan, ONE barrier per chunk. Every wave computes
// the FULL u' = u - w@S itself (24 MFMA, redundant across waves — MFMA is 5%
// utilized, duplication is free) so the u' publish barrier disappears: the
// D-layout -> B-frag lane transpose goes through a PER-WAVE private LDS
// scratch (same-wave write->read: lgkmcnt only, no barrier). Per iteration:
// [barrier] -> preload all current-buffer frags -> DMA next chunk (two NAMED
// LDS buffers; all reads precede issue) -> u' both halves -> scratch
// transpose -> S update -> o (wv2/3, no DMA on them) -> [barrier]. The single
// barrier publishes ST and drains the DMA issued a full iteration earlier.
// ---------------------------------------------------------------------------
__global__ __launch_bounds__(512, 1) void k_scan(const short* __restrict__ RECg,
                                                 const float* __restrict__ Uws,
                                                 float* __restrict__ Out,
                                                 float* __restrict__ Sout) {
    __shared__ __attribute__((aligned(16))) short bufA[RECSZ];
    __shared__ __attribute__((aligned(16))) short bufB[RECSZ];
    __shared__ short STh[DVB * PS], STl[DVB * PS];
    __shared__ short uSh[8][16 * PC], uSl[8][16 * PC];   // per-wave u' scratch

    const int t = threadIdx.x, lane = t & 63, wv = t >> 6;
    const int quad = (t >> 4) & 3, l15 = t & 15;
    const int db = blockIdx.x >> 4, bhi = blockIdx.x & 15;
    const int vcol = db * DVB;
    const int r02 = (wv & 1) * 16;         // o ci-tile for wv2/3
    const int dk0 = wv * 16;               // S dk-tile per wave
    const size_t gb = (size_t)bhi * NCH;   // chunk index base
    const bool owv = (wv == 2 || wv == 3); // o-computing waves (no DMA)
    const int widx = (wv < 2) ? wv : wv - 2;   // 0..5 for the 6 DMA waves

    f32x4 accS = {0.f, 0.f, 0.f, 0.f};
    float puA[8], puB[8];
#pragma unroll
    for (int r = 0; r < 8; ++r) { puA[r] = 0.f; puB[r] = 0.f; }
    short* const myUh = &uSh[wv][0];
    short* const myUl = &uSl[wv][0];

    // 44 x 1KB record units striped over the 6 non-o waves
    auto dma_chunk = [&](int cc, short* dst) {
        const short* src = RECg + (size_t)(gb + cc) * RECSZ;
#pragma unroll
        for (int k = 0; k < 8; ++k) {
            int q = widx + 6 * k;
            if (q < 44) dma1k(src + q * 512, dst + q * 512, lane);
        }
    };
    auto pref_u = [&](int cc, float* p) {
        const size_t ub = (gb + cc) * 4096;
#pragma unroll
        for (int r = 0; r < 4; ++r) {
            p[r]     = Uws[ub + (size_t)(quad * 4 + r) * DK + vcol + l15];
            p[4 + r] = Uws[ub + (size_t)(16 + quad * 4 + r) * DK + vcol + l15];
        }
    };

    for (int e = t; e < DVB * PS; e += 512) { STh[e] = 0; STl[e] = 0; }
    if (!owv) dma_chunk(0, bufA);
    pref_u(0, puA);
    __syncthreads();   // prologue: full drain (DMA(0) + pu(0) + ST zero)

    auto body = [&](int cid, const short* R, short* Wb, const float* puC, float* puN) {
        // ---- A: preload ALL current-buffer operands (before DMA issue) ----
        short8 kth = fldz32(R + OKTH, dk0, lane);
        short8 ktl = fldz32(R + OKTL, dk0, lane);
        short8 Sh[4], Sl[4], WhA[4], WlA[4], WhB[4], WlB[4];
#pragma unroll
        for (int ks = 0; ks < 4; ++ks) {
            Sh[ks]  = fld(STh, 0, PS, ks * 32, lane);
            Sl[ks]  = fld(STl, 0, PS, ks * 32, lane);
            WhA[ks] = fldz128(R + OWH, 0,  ks, lane);
            WlA[ks] = fldz128(R + OWL, 0,  ks, lane);
            WhB[ks] = fldz128(R + OWH, 16, ks, lane);
            WlB[ks] = fldz128(R + OWL, 16, ks, lane);
        }
        short8 qf0 = {}, qf1 = {}, qf2 = {}, qf3 = {}, bah = {}, bal = {};
        if (owv) {
            qf0 = fldz128(R + OQ, r02, 0, lane);
            qf1 = fldz128(R + OQ, r02, 1, lane);
            qf2 = fldz128(R + OQ, r02, 2, lane);
            qf3 = fldz128(R + OQ, r02, 3, lane);
            bah = fldz32(R + OATH, r02, lane);
            bal = fldz32(R + OATL, r02, lane);
        }
        // ---- B: next-chunk prefetch (drained only at the end barrier) ----
        if (cid + 1 < NCH) {
            if (!owv) dma_chunk(cid + 1, Wb);
            pref_u(cid + 1, puN);
        }
        // ---- C: full u' (both c-halves) into private scratch ----
        {
            f32x4 u0 = {-puC[0], -puC[1], -puC[2], -puC[3]};
            f32x4 u1 = {0.f, 0.f, 0.f, 0.f}, u2 = {0.f, 0.f, 0.f, 0.f};
#pragma unroll
            for (int ks = 0; ks < 4; ++ks) {
                u0 = mf(WhA[ks], Sh[ks], u0);
                u1 = mf(WhA[ks], Sl[ks], u1);
                u2 = mf(WlA[ks], Sh[ks], u2);
            }
            f32x4 us = u0 + u1 + u2;            // = w@S - u (c rows 0-15)
            s16x4 h4, l4;
#pragma unroll
            for (int r = 0; r < 4; ++r) {
                unsigned p = split_bf16(-us[r]);
                h4[r] = (short)(p >> 16); l4[r] = (short)(p & 0xffffu);
            }
            *(s16x4*)(myUh + l15 * PC + quad * 4) = h4;
            *(s16x4*)(myUl + l15 * PC + quad * 4) = l4;
        }
        {
            f32x4 u0 = {-puC[4], -puC[5], -puC[6], -puC[7]};
            f32x4 u1 = {0.f, 0.f, 0.f, 0.f}, u2 = {0.f, 0.f, 0.f, 0.f};
#pragma unroll
            for (int ks = 0; ks < 4; ++ks) {
                u0 = mf(WhB[ks], Sh[ks], u0);
                u1 = mf(WhB[ks], Sl[ks], u1);
                u2 = mf(WlB[ks], Sh[ks], u2);
            }
            f32x4 us = u0 + u1 + u2;            // c rows 16-31
            s16x4 h4, l4;
#pragma unroll
            for (int r = 0; r < 4; ++r) {
                unsigned p = split_bf16(-us[r]);
                h4[r] = (short)(p >> 16); l4[r] = (short)(p & 0xffffu);
            }
            *(s16x4*)(myUh + l15 * PC + 16 + quad * 4) = h4;
            *(s16x4*)(myUl + l15 * PC + 16 + quad * 4) = l4;
        }
        // ---- D: same-wave B-frag readback (lgkm wait only, no barrier) ----
        short8 buh = fld(myUh, 0, PC, 0, lane);
        short8 bul = fld(myUl, 0, PC, 0, lane);
        // ---- E: S update + ST replanes ----
        {
            f32x4 z = {0.f, 0.f, 0.f, 0.f};
            f32x4 ta = mf(ktl, buh, z);         // independent
            f32x4 tb = mf(kth, bul, z);         // independent
            accS = mf(kth, buh, accS);
            accS += ta + tb;
            s16x4 h4, l4;
#pragma unroll
            for (int r = 0; r < 4; ++r) {
                unsigned p = split_bf16(accS[r]);
                h4[r] = (short)(p >> 16); l4[r] = (short)(p & 0xffffu);
            }
            *(s16x4*)(STh + l15 * PS + dk0 + quad * 4) = h4;   // S^T[dv][dk]
            *(s16x4*)(STl + l15 * PS + dk0 + quad * 4) = l4;
        }
        // ---- F: o = q@S + attn@u' on wv2/3 (uses pre-update S in regs) ----
        if (owv) {
            f32x4 z = {0.f, 0.f, 0.f, 0.f};
            f32x4 oa = mf(Sh[0], qf0, z), ob_ = mf(Sl[0], qf0, z);
            f32x4 oc2 = mf(Sh[1], qf1, z), od = mf(Sl[1], qf1, z);
            oa = mf(Sh[2], qf2, oa); ob_ = mf(Sl[2], qf2, ob_);
            oc2 = mf(Sh[3], qf3, oc2); od = mf(Sl[3], qf3, od);
            f32x4 osum = (oa + ob_) + (oc2 + od);
            f32x4 oc = mf(buh, bah, mf(buh, bal, mf(bul, bah, osum)));
            const size_t ob = ((size_t)bhi * LSEQ + (size_t)cid * C) * DK;
            *(f32x4*)(Out + ob + (size_t)(r02 + l15) * DK + vcol + quad * 4) = oc;
        }
        __syncthreads();   // single barrier: ST published, DMA drained
    };

    for (int cp = 0; cp < NCH / 2; ++cp) {
        body(2 * cp,     bufA, bufB, puA, puB);
        body(2 * cp + 1, bufB, bufA, puB, puA);
    }

    // final state: Sout[bh][dk][dv]
#pragma unroll
    for (int r = 0; r < 4; ++r)
        Sout[(size_t)bhi * DK * DV + (size_t)(dk0 + quad * 4 + r) * DV + vcol + l15] = accS[r];
}

extern "C" void kernel_launch(void* const* d_in, const int* in_sizes, int n_in,
                              void* d_out, int out_size, void* d_ws, size_t ws_size,
                              hipStream_t stream) {
    const float* Q    = (const float*)d_in[0];
    const float* K    = (const float*)d_in[1];
    const float* V    = (const float*)d_in[2];
    const float* Beta = (const float*)d_in[3];

    float* Out  = (float*)d_out;
    float* Sout = Out + (size_t)BH * LSEQ * DV;

    short* RECg = (short*)d_ws;                                  // 88 MiB records
    float* Uws  = (float*)(RECg + (size_t)BH * NCH * RECSZ);     // +32 MiB

    hipLaunchKernelGGL(k_prep, dim3(BH * NCH), dim3(512), 0, stream,
                       Q, K, V, Beta, RECg, Uws);
    hipLaunchKernelGGL(k_scan, dim3(BH * NDVB), dim3(512), 0, stream,
                       RECg, Uws, Out, Sout);
}

// Round 9
// 337.795 us; speedup vs baseline: 1.2742x; 1.2742x over previous
//
#include <hip/hip_runtime.h>
#include <cstddef>

#define BH   16
#define LSEQ 4096
#define DK   128
#define DV   128
#define C    32
#define NCH  128
#define DVB  16      // dv per scan block
#define NDVB 8
#define PP   136     // prep row-plane pitch (shorts)
#define PC   40      // pitch for [*][32] col planes (kT/vT/T/uT)
#define PS   136     // ST pitch
#define AP   33      // fp32 pitch for 32x32 A
#define WP   136     // prep w-plane LDS pitch
#define ATP  40      // prep attn-plane LDS pitch

// per-(bh,chunk) contiguous record in workspace (shorts):
// [QH 4096 | WH 4096 | WL 4096 | KTH 4096 | KTL 4096 | ATH 1024 | ATL 1024]
// QH/WH/WL: z128 layout (row*128, slot c^(row&7)).
// KTH/KTL/ATH/ATL: z64 FOLD layout — row-pairs packed into 128B rows:
//   off(d,g) = (d>>1)*64 + (d&1)*32 + ((g ^ ((d>>1)&3)) << 3)
#define RECSZ 22528
#define OQ    0
#define OWH   4096
#define OWL   8192
#define OKTH  12288
#define OKTL  16384
#define OATH  20480
#define OATL  21504

typedef __attribute__((ext_vector_type(4))) float f32x4;
typedef __attribute__((ext_vector_type(8))) short short8;
typedef __attribute__((ext_vector_type(4))) short s16x4;

// split-bf16: x ~= hi + lo, each bf16 rne. Returns (hi<<16)|lo.
__device__ inline unsigned split_bf16(float x) {
    unsigned u = __builtin_bit_cast(unsigned, x);
    unsigned r = u + 0x7fffu + ((u >> 16) & 1u);
    unsigned h = r >> 16;
    float hf = __builtin_bit_cast(float, r & 0xffff0000u);
    float res = x - hf;
    unsigned u2 = __builtin_bit_cast(unsigned, res);
    unsigned r2 = u2 + 0x7fffu + ((u2 >> 16) & 1u);
    return (h << 16) | (r2 >> 16);
}
__device__ inline short hi_bf16(float x) {
    unsigned u = __builtin_bit_cast(unsigned, x);
    return (short)((u + 0x7fffu + ((u >> 16) & 1u)) >> 16);
}
__device__ inline short trunc_bf16(float x) {   // x already exactly bf16
    return (short)(__builtin_bit_cast(unsigned, x) >> 16);
}

// classic pitched frag load: lane holds P[row0+(lane&15)][k0 + (lane>>4)*8 + j]
__device__ inline short8 fld(const short* P, int row0, int pitch, int k0, int lane) {
    return *(const short8*)(P + (row0 + (lane & 15)) * pitch + k0 + ((lane >> 4) << 3));
}
// swizzled pitch-128 plane frag load ([32][128], slot c XOR row&7)
__device__ inline short8 fldz128(const short* P, int row0, int ks, int lane) {
    int row = row0 + (lane & 15);
    int c = ks * 4 + (lane >> 4);
    return *(const short8*)(P + row * 128 + ((c ^ (row & 7)) << 3));
}
// z64-FOLD plane frag load (row-pairs in 128B rows), K=32. 2-way banks.
__device__ inline short8 fldz64(const short* P, int row0, int lane) {
    int d = row0 + (lane & 15);
    int g = lane >> 4;
    return *(const short8*)(P + (d >> 1) * 64 + (d & 1) * 32 + ((g ^ ((d >> 1) & 3)) << 3));
}
__device__ inline f32x4 mf(short8 a, short8 b, f32x4 c) {
    return __builtin_amdgcn_mfma_f32_16x16x32_bf16(a, b, c, 0, 0, 0);
}
__device__ inline void build_ifrags(int lane, short8& Iev, short8& Iod) {
    int n = lane & 15, q = lane >> 4;
#pragma unroll
    for (int j = 0; j < 8; ++j) {
        Iev[j] = (q * 8 + j == n)      ? (short)0x3F80 : (short)0;
        Iod[j] = (q * 8 + j == n + 16) ? (short)0x3F80 : (short)0;
    }
}
// async global->LDS, 1KB per wave-call (lane i -> ldsbase + i*16)
__device__ inline void dma1k(const short* g, short* l, int lane) {
    __builtin_amdgcn_global_load_lds(
        (const __attribute__((address_space(1))) unsigned int*)(g + lane * 8),
        (__attribute__((address_space(3))) unsigned int*)l, 16, 0, 0);
}

// ---------------------------------------------------------------------------
// Kernel 1: per-chunk precompute. 512 threads. All record-plane global stores
// now go through LDS and a final COALESCED copy phase (one contiguous 16B per
// thread, inverse-swizzled LDS source) instead of 8B scattered stores.
// ---------------------------------------------------------------------------
__global__ __launch_bounds__(512) void k_prep(const float* __restrict__ Q,
                                              const float* __restrict__ K,
                                              const float* __restrict__ V,
                                              const float* __restrict__ Beta,
                                              short* __restrict__ RECg,
                                              float* __restrict__ Uws) {
    __shared__ short knh[C * PP], knl[C * PP], vh[C * PP], vl[C * PP], qh[C * PP];
    __shared__ short knTh[DK * PC], knTl[DK * PC], vTh[DK * PC], vTl[DK * PC];
    __shared__ short Th[C * PC], Tl[C * PC];
    __shared__ short wTh[C * WP], wTl[C * WP];      // w bounce planes
    __shared__ short aTh[C * ATP], aTl[C * ATP];    // attn bounce planes
    __shared__ float A[C * AP];
    __shared__ float sbeta[C];

    const int t = threadIdx.x, lane = t & 63, wv = t >> 6;
    const int quad = (t >> 4) & 3, l15 = t & 15;
    const int g = blockIdx.x;                       // bh*128 + cid
    const size_t base = (size_t)g * (C * DK);
    short* rec = RECg + (size_t)g * RECSZ;
    short8 Iev, Iod;
    build_ifrags(lane, Iev, Iod);

    if (t < C) sbeta[t] = Beta[(size_t)(g >> 7) * LSEQ + (size_t)(g & 127) * C + t];

    // ---- P0: load K,V,Q (8 floats/thread); norms; row planes + QH record ----
    {
        const int sr = t >> 4, sc = (t & 15) * 8;
        f32x4 kk[2], vv[2], qq[2];
#pragma unroll
        for (int g4 = 0; g4 < 2; ++g4) {
            kk[g4] = *(const f32x4*)(K + base + 8 * t + 4 * g4);
            vv[g4] = *(const f32x4*)(V + base + 8 * t + 4 * g4);
            qq[g4] = *(const f32x4*)(Q + base + 8 * t + 4 * g4);
        }
        float ssk = 0.f, ssq = 0.f;
#pragma unroll
        for (int g4 = 0; g4 < 2; ++g4) {
#pragma unroll
            for (int e = 0; e < 4; ++e) {
                ssk += kk[g4][e] * kk[g4][e];
                ssq += qq[g4][e] * qq[g4][e];
            }
        }
        ssk += __shfl_xor(ssk, 1); ssk += __shfl_xor(ssk, 2);
        ssk += __shfl_xor(ssk, 4); ssk += __shfl_xor(ssk, 8);
        ssq += __shfl_xor(ssq, 1); ssq += __shfl_xor(ssq, 2);
        ssq += __shfl_xor(ssq, 4); ssq += __shfl_xor(ssq, 8);
        const float rk = rsqrtf(ssk + 1e-6f), rq = rsqrtf(ssq + 1e-6f);
        short8 h8, l8, q8;
#pragma unroll
        for (int e = 0; e < 8; ++e) {
            unsigned p = split_bf16(kk[e >> 2][e & 3] * rk);
            h8[e] = (short)(p >> 16); l8[e] = (short)(p & 0xffffu);
        }
        *(short8*)(knh + sr * PP + sc) = h8;
        *(short8*)(knl + sr * PP + sc) = l8;
#pragma unroll
        for (int e = 0; e < 8; ++e) {
            unsigned p = split_bf16(vv[e >> 2][e & 3]);
            h8[e] = (short)(p >> 16); l8[e] = (short)(p & 0xffffu);
        }
        *(short8*)(vh + sr * PP + sc) = h8;
        *(short8*)(vl + sr * PP + sc) = l8;
#pragma unroll
        for (int e = 0; e < 8; ++e) q8[e] = hi_bf16(qq[e >> 2][e & 3] * rq);
        *(short8*)(qh + sr * PP + sc) = q8;
        int c = sc >> 3;
        *(short8*)(rec + OQ + sr * 128 + ((c ^ (sr & 7)) << 3)) = q8;   // coalesced per row
    }
    __syncthreads();

    // ---- P1: G tiles -> A (strict lower, -beta scaled); attn tiles -> aT LDS ----
    if (wv < 3) {
        const int a0 = (wv == 0) ? 0 : 16;      // m rows (ci for attn)
        const int b0 = (wv == 2) ? 16 : 0;      // n rows (cj for attn)
        f32x4 acc = {0.f, 0.f, 0.f, 0.f};
#pragma unroll
        for (int ks = 0; ks < 4; ++ks) {
            short8 ah = fld(knh, a0, PP, ks * 32, lane);
            short8 al = fld(knl, a0, PP, ks * 32, lane);
            short8 bh_ = fld(knh, b0, PP, ks * 32, lane);
            short8 bl_ = fld(knl, b0, PP, ks * 32, lane);
            acc = mf(ah, bh_, mf(ah, bl_, mf(al, bh_, acc)));
        }
#pragma unroll
        for (int r = 0; r < 4; ++r) {
            int row = a0 + quad * 4 + r, col = b0 + l15;
            A[row * AP + col] = (row > col) ? -sbeta[row] * acc[r] : 0.f;
        }
        // attn tile: A-op = kn rows cj (m=cj), B-op = qh rows ci (n=ci)
        f32x4 at = {0.f, 0.f, 0.f, 0.f};
#pragma unroll
        for (int ks = 0; ks < 4; ++ks) {
            short8 kh_ = fld(knh, b0, PP, ks * 32, lane);
            short8 kl_ = fld(knl, b0, PP, ks * 32, lane);
            short8 qf = fld(qh, a0, PP, ks * 32, lane);
            at = mf(kh_, qf, mf(kl_, qf, at));
        }
        s16x4 h4, l4;
#pragma unroll
        for (int r = 0; r < 4; ++r) {
            int cj = b0 + quad * 4 + r, ci = a0 + l15;
            float v = (cj <= ci) ? at[r] : 0.f;
            unsigned p = split_bf16(v);
            h4[r] = (short)(p >> 16); l4[r] = (short)(p & 0xffffu);
        }
        *(s16x4*)(aTh + (a0 + l15) * ATP + b0 + quad * 4) = h4;
        *(s16x4*)(aTl + (a0 + l15) * ATP + b0 + quad * 4) = l4;
    } else if (wv == 3) {
        // zero the (rows 0-15, cols 16-31) upper tile of A and attn
#pragma unroll
        for (int r = 0; r < 4; ++r) A[l15 * AP + 16 + quad * 4 + r] = 0.f;
        s16x4 z = {0, 0, 0, 0};
        *(s16x4*)(aTh + l15 * ATP + 16 + quad * 4) = z;
        *(s16x4*)(aTl + l15 * ATP + 16 + quad * 4) = z;
    }
    __syncthreads();

    // ---- P2: transposes (LDS only) split across wave pairs; subst on wv3 ----
    auto tplane1 = [&](const short* src, short* dst, int c0) {
#pragma unroll
        for (int ks = 0; ks < 4; ++ks) {
            short8 fr = fld(src, c0, PP, ks * 32, lane);
            f32x4 z = {0.f, 0.f, 0.f, 0.f};
            f32x4 cA = mf(fr, Iev, z);
            f32x4 cB = mf(fr, Iod, z);
            s16x4 sA, sB;
#pragma unroll
            for (int r = 0; r < 4; ++r) { sA[r] = trunc_bf16(cA[r]); sB[r] = trunc_bf16(cB[r]); }
            *(s16x4*)(dst + (ks * 32 + l15) * PC + c0 + quad * 4) = sA;
            *(s16x4*)(dst + (ks * 32 + 16 + l15) * PC + c0 + quad * 4) = sB;
        }
    };
    if (wv == 0)      tplane1(knh, knTh, 0);
    else if (wv == 4) tplane1(knh, knTh, 16);
    else if (wv == 1) tplane1(knl, knTl, 0);
    else if (wv == 5) tplane1(knl, knTl, 16);
    else if (wv == 2) tplane1(vh, vTh, 0);
    else if (wv == 6) tplane1(vh, vTh, 16);
    else if (wv == 7) { tplane1(vl, vTl, 0); tplane1(vl, vTl, 16); }
    else if (lane < C) {
        const int j = lane;       // forward substitution (upper of A is zero)
        for (int i = 1; i < C; ++i) {
            float upd = 0.f;
            for (int kk2 = 1; kk2 < i; ++kk2) upd += A[i * AP + kk2] * A[kk2 * AP + j];
            if (j < i) A[i * AP + j] += upd;
        }
    }
    __syncthreads();

    // ---- P3: T' = (A + I) * diag(beta) -> Th/Tl ----
    if (t < 256) {
        int tr = t >> 3, tc = (t & 7) * 4;
        s16x4 h4, l4;
#pragma unroll
        for (int e = 0; e < 4; ++e) {
            int j = tc + e;
            float val = ((tr == j) ? 1.f : (tr > j ? A[tr * AP + j] : 0.f)) * sbeta[j];
            unsigned p = split_bf16(val);
            h4[e] = (short)(p >> 16); l4[e] = (short)(p & 0xffffu);
        }
        *(s16x4*)(Th + tr * PC + tc) = h4;
        *(s16x4*)(Tl + tr * PC + tc) = l4;
    }
    __syncthreads();

    // ---- P4: u = T'@v (fp32 -> Uws) on wv0-3, w = T'@kn (-> wT LDS) on wv4-7 ----
    {
        const int ci0 = (wv & 1) * 16;
        short8 bTh = fld(Th, ci0, PC, 0, lane);
        short8 bTl = fld(Tl, ci0, PC, 0, lane);
        if (wv < 4) {
            const int tb = (wv >> 1) * 4;       // slab range: 0-3 or 4-7
#pragma unroll
            for (int k = 0; k < 4; ++k) {
                int tt = tb + k;
                short8 ah = fld(vTh, tt * 16, PC, 0, lane);
                short8 al = fld(vTl, tt * 16, PC, 0, lane);
                f32x4 z = {0.f, 0.f, 0.f, 0.f};
                f32x4 acc = mf(ah, bTh, mf(ah, bTl, mf(al, bTh, z)));
                // line-complete per instruction (16 rows x 64B segments)
                *(f32x4*)(Uws + (size_t)g * 4096 + (size_t)(ci0 + l15) * DK + tt * 16 + quad * 4) = acc;
            }
        } else {
            const int tb = ((wv - 4) >> 1) * 4;
#pragma unroll
            for (int k = 0; k < 4; ++k) {
                int tt = tb + k;
                short8 ah = fld(knTh, tt * 16, PC, 0, lane);
                short8 al = fld(knTl, tt * 16, PC, 0, lane);
                f32x4 z = {0.f, 0.f, 0.f, 0.f};
                f32x4 acc = mf(ah, bTh, mf(ah, bTl, mf(al, bTh, z)));
                s16x4 h4, l4;
#pragma unroll
                for (int r = 0; r < 4; ++r) {
                    unsigned p = split_bf16(acc[r]);
                    h4[r] = (short)(p >> 16); l4[r] = (short)(p & 0xffffu);
                }
                *(s16x4*)(wTh + (ci0 + l15) * WP + tt * 16 + quad * 4) = h4;
                *(s16x4*)(wTl + (ci0 + l15) * WP + tt * 16 + quad * 4) = l4;
            }
        }
    }
    __syncthreads();

    // ---- P5: coalesced copy-out (one contiguous 16B global store/thread) ----
    {
        // KT planes: z64 fold. o = t*8 -> d = (t>>3)*2 + ((t>>2)&1),
        // g = (t&3) ^ ((t>>3)&3); src col g*8 of pitched knT row d.
        const int dK = ((t >> 3) << 1) + ((t >> 2) & 1);
        const int gK = (t & 3) ^ ((t >> 3) & 3);
        *(short8*)(rec + OKTH + t * 8) = *(const short8*)(knTh + dK * PC + gK * 8);
        *(short8*)(rec + OKTL + t * 8) = *(const short8*)(knTl + dK * PC + gK * 8);
        // W planes: z128. o = t*8 -> row = t>>4, g = (t&15) ^ (row&7).
        const int rW = t >> 4;
        const int gW = (t & 15) ^ (rW & 7);
        *(short8*)(rec + OWH + t * 8) = *(const short8*)(wTh + rW * WP + gW * 8);
        *(short8*)(rec + OWL + t * 8) = *(const short8*)(wTl + rW * WP + gW * 8);
        // AT planes: z64 fold, 1024 shorts each (threads 0-127).
        if (t < 128) {
            const int dA = ((t >> 3) << 1) + ((t >> 2) & 1);
            const int gA = (t & 3) ^ ((t >> 3) & 3);
            *(short8*)(rec + OATH + t * 8) = *(const short8*)(aTh + dA * ATP + gA * 8);
            *(short8*)(rec + OATL + t * 8) = *(const short8*)(aTl + dA * ATP + gA * 8);
        }
    }
}

// ---------------------------------------------------------------------------
// Kernel 2: sequential chunk scan — round-2 champion structure, with the
// [*][32] plane reads (kT, attn) moved to the z64-fold layout (2-way banks
// instead of 4-way). Everything else identical to the 140us champion.
// ---------------------------------------------------------------------------
__global__ __launch_bounds__(512, 1) void k_scan(const short* __restrict__ RECg,
                                                 const float* __restrict__ Uws,
                                                 float* __restrict__ Out,
                                                 float* __restrict__ Sout) {
    __shared__ __attribute__((aligned(16))) short bALL[2][RECSZ];
    __shared__ short STh[DVB * PS], STl[DVB * PS];
    __shared__ short uTh[DVB * PC], uTl[DVB * PC];

    const int t = threadIdx.x, lane = t & 63, wv = t >> 6;
    const int quad = (t >> 4) & 3, l15 = t & 15;
    const int db = blockIdx.x >> 4, bhi = blockIdx.x & 15;
    const int vcol = db * DVB;
    const int r0 = (wv & 1) * 16;          // ci tile for wv0/1
    const int dk0 = wv * 16;               // S dk-tile per wave
    const size_t gb = (size_t)bhi * NCH;   // chunk index base

    f32x4 accS = {0.f, 0.f, 0.f, 0.f};
    float pu[4] = {0.f, 0.f, 0.f, 0.f};

    // wv2-7 copy the whole 44KB record (44 x 1KB units, strided by 6 waves)
    auto dma_chunk = [&](int cc, int s) {
        if (wv < 2) return;
        const short* src = RECg + (size_t)(gb + cc) * RECSZ;
        short* dst = bALL[s];
#pragma unroll
        for (int k = 0; k < 8; ++k) {
            int q = (wv - 2) + 6 * k;
            if (q < 44) dma1k(src + q * 512, dst + q * 512, lane);
        }
    };
    auto pref_u = [&](int cc) {
        if (wv < 2) {
            const size_t ub = (gb + cc) * 4096;
#pragma unroll
            for (int r = 0; r < 4; ++r)
                pu[r] = Uws[ub + (size_t)(r0 + quad * 4 + r) * DK + vcol + l15];
        }
    };

    for (int e = t; e < DVB * PS; e += 512) { STh[e] = 0; STl[e] = 0; }
    dma_chunk(0, 0);
    pref_u(0);
    __syncthreads();   // drains DMA(0) + pu(0)

    for (int cid = 0; cid < NCH; ++cid) {
        const int cur = cid & 1;
        const short* pC = bALL[cur];
        f32x4 oc = {0.f, 0.f, 0.f, 0.f};

        // preload S-update operands for stage 2 (buffer `cur` is stable all
        // iteration). These reads PRECEDE any DMA issue in program order, so
        // no conservative vmcnt wait lands on them.
        short8 kth = fldz64(pC + OKTH, dk0, lane);
        short8 ktl = fldz64(pC + OKTL, dk0, lane);
        short8 bah = {}, bal = {};

        if (wv >= 2) {
            // ---- producers: issue next-chunk DMA now; mid-sync drain
            //      overlaps the barrier wait for wv0/1's stage 1 ----
            if (cid + 1 < NCH) dma_chunk(cid + 1, cur ^ 1);
        } else {
            // ---- consumers: capture u, prefetch next u, stage 1 ----
            float p0 = pu[0], p1 = pu[1], p2 = pu[2], p3 = pu[3];
            if (cid + 1 < NCH) pref_u(cid + 1);

            f32x4 u0 = {-p0, -p1, -p2, -p3};
            f32x4 u1 = {0.f, 0.f, 0.f, 0.f}, u2 = {0.f, 0.f, 0.f, 0.f};
            f32x4 o1 = {0.f, 0.f, 0.f, 0.f};
#pragma unroll
            for (int ks = 0; ks < 4; ++ks) {
                short8 wh_ = fldz128(pC + OWH, r0, ks, lane);
                short8 wl_ = fldz128(pC + OWL, r0, ks, lane);
                short8 sh_ = fld(STh, 0, PS, ks * 32, lane);
                short8 sl_ = fld(STl, 0, PS, ks * 32, lane);
                short8 qf = fldz128(pC + OQ, r0, ks, lane);
                u0 = mf(wh_, sh_, u0);          // independent chains
                u1 = mf(wh_, sl_, u1);
                u2 = mf(wl_, sh_, u2);
                oc = mf(sh_, qf, oc);           // o^T[dv][ci]
                o1 = mf(sl_, qf, o1);
            }
            oc += o1;
            f32x4 us = u0 + u1 + u2;            // = w@S - u
            s16x4 h4, l4;
#pragma unroll
            for (int r = 0; r < 4; ++r) {
                unsigned p = split_bf16(-us[r]);
                h4[r] = (short)(p >> 16); l4[r] = (short)(p & 0xffffu);
            }
            *(s16x4*)(uTh + l15 * PC + r0 + quad * 4) = h4;   // u'^T[dv][c]
            *(s16x4*)(uTl + l15 * PC + r0 + quad * 4) = l4;
            // preload attn tiles for stage 2
            bah = fldz64(pC + OATH, r0, lane);
            bal = fldz64(pC + OATL, r0, lane);
        }
        __syncthreads();   // mid: uT visible; wv2-7's DMA drain overlapped here

        // ---- stage 2: o finish + S accumulate + S replanes ----
        short8 buh = fld(uTh, 0, PC, 0, lane);
        short8 bul = fld(uTl, 0, PC, 0, lane);
        if (wv < 2) {
            oc = mf(buh, bah, mf(buh, bal, mf(bul, bah, oc)));
            const size_t ob = ((size_t)bhi * LSEQ + (size_t)cid * C) * DK;
            *(f32x4*)(Out + ob + (size_t)(r0 + l15) * DK + vcol + quad * 4) = oc;
        }
        {
            f32x4 z = {0.f, 0.f, 0.f, 0.f};
            f32x4 tband = mf(kth, bul, mf(ktl, buh, z));
            accS = mf(kth, buh, accS);
            accS += tband;
            s16x4 h4, l4;
#pragma unroll
            for (int r = 0; r < 4; ++r) {
                unsigned p = split_bf16(accS[r]);
                h4[r] = (short)(p >> 16); l4[r] = (short)(p & 0xffffu);
            }
            *(s16x4*)(STh + l15 * PS + dk0 + quad * 4) = h4;   // S^T[dv][dk]
            *(s16x4*)(STl + l15 * PS + dk0 + quad * 4) = l4;
        }
        __syncthreads();   // end: ST visible; next buffer fully staged
    }

    // final state: Sout[bh][dk][dv]
#pragma unroll
    for (int r = 0; r < 4; ++r)
        Sout[(size_t)bhi * DK * DV + (size_t)(dk0 + quad * 4 + r) * DV + vcol + l15] = accS[r];
}

extern "C" void kernel_launch(void* const* d_in, const int* in_sizes, int n_in,
                              void* d_out, int out_size, void* d_ws, size_t ws_size,
                              hipStream_t stream) {
    const float* Q    = (const float*)d_in[0];
    const float* K    = (const float*)d_in[1];
    const float* V    = (const float*)d_in[2];
    const float* Beta = (const float*)d_in[3];

    float* Out  = (float*)d_out;
    float* Sout = Out + (size_t)BH * LSEQ * DV;

    short* RECg = (short*)d_ws;                                  // 88 MiB records
    float* Uws  = (float*)(RECg + (size_t)BH * NCH * RECSZ);     // +32 MiB

    hipLaunchKernelGGL(k_prep, dim3(BH * NCH), dim3(512), 0, stream,
                       Q, K, V, Beta, RECg, Uws);
    hipLaunchKernelGGL(k_scan, dim3(BH * NDVB), dim3(512), 0, stream,
                       RECg, Uws, Out, Sout);
}